// Round 1
// baseline (1357.998 us; speedup 1.0000x reference)
//
#include <hip/hip_runtime.h>
#include <stdint.h>

#define K 32
#define BLOCK 256
#define EPB (BLOCK * 8)   // elements per epoch (two float4 loads per thread)

// Pack a key into a uint64 whose unsigned ordering == (key asc, then index desc).
// Larger packed = larger key; among equal keys, smaller index wins (matches lax.top_k).
__device__ __forceinline__ unsigned long long pack_key(float r, float p, unsigned idx) {
    float key = logf(r) / p;
    unsigned kb = __float_as_uint(key);
    unsigned ord = (kb & 0x80000000u) ? ~kb : (kb | 0x80000000u);
    return ((unsigned long long)ord << 32) | (unsigned long long)(~idx);
}

__device__ __forceinline__ void heap_siftdown(volatile unsigned long long* H, int size,
                                              unsigned long long x) {
    // H is a min-heap of `size` entries; place x starting at root.
    int i = 0;
    for (;;) {
        int l = 2 * i + 1;
        if (l >= size) break;
        int r = l + 1;
        int m = l;
        unsigned long long vm = H[l];
        if (r < size) {
            unsigned long long vr = H[r];
            if (vr < vm) { m = r; vm = vr; }
        }
        if (vm >= x) break;
        H[i] = vm;
        i = m;
    }
    H[i] = x;
}

__global__ __launch_bounds__(BLOCK) void topk_race_kernel(
    const float* __restrict__ probs,
    const float* __restrict__ rnd,
    int* __restrict__ out,
    int V)
{
    __shared__ unsigned long long s_heap[K];      // block-wide top-K min-heap (packed)
    __shared__ unsigned long long s_queue[EPB];   // candidate queue for this epoch
    __shared__ int s_qcount;
    __shared__ unsigned long long s_thr;          // current heap min (filter threshold)

    const int row = blockIdx.x;
    const int tid = threadIdx.x;
    const float* __restrict__ prow = probs + (size_t)row * V;
    const float* __restrict__ rrow = rnd   + (size_t)row * V;

    if (tid < K) s_heap[tid] = 0ull;
    if (tid == 0) { s_qcount = 0; s_thr = 0ull; }
    __syncthreads();

    const int nepoch = (V + EPB - 1) / EPB;
    for (int e = 0; e < nepoch; ++e) {
        const unsigned long long thr = s_thr;   // broadcast read, stable within epoch
        const int eb = e * EPB;
        const int b0 = eb + tid * 4;            // first float4
        const int b1 = eb + BLOCK * 4 + tid * 4; // second float4

        unsigned long long pk[8];
        int npk = 0;

        if (b0 + 3 < V) {
            const float4 p = *(const float4*)(prow + b0);
            const float4 r = *(const float4*)(rrow + b0);
            pk[npk++] = pack_key(r.x, p.x, (unsigned)(b0 + 0));
            pk[npk++] = pack_key(r.y, p.y, (unsigned)(b0 + 1));
            pk[npk++] = pack_key(r.z, p.z, (unsigned)(b0 + 2));
            pk[npk++] = pack_key(r.w, p.w, (unsigned)(b0 + 3));
        }
        if (b1 + 3 < V) {
            const float4 p = *(const float4*)(prow + b1);
            const float4 r = *(const float4*)(rrow + b1);
            pk[npk++] = pack_key(r.x, p.x, (unsigned)(b1 + 0));
            pk[npk++] = pack_key(r.y, p.y, (unsigned)(b1 + 1));
            pk[npk++] = pack_key(r.z, p.z, (unsigned)(b1 + 2));
            pk[npk++] = pack_key(r.w, p.w, (unsigned)(b1 + 3));
        }

        #pragma unroll
        for (int j = 0; j < 8; ++j) {
            if (j < npk && pk[j] > thr) {
                int slot = atomicAdd(&s_qcount, 1);
                s_queue[slot] = pk[j];
            }
        }

        __syncthreads();
        if (tid == 0) {
            const int n = s_qcount;
            unsigned long long root = s_heap[0];
            for (int q = 0; q < n; ++q) {
                unsigned long long x = s_queue[q];
                if (x > root) {
                    heap_siftdown(s_heap, K, x);
                    root = s_heap[0];
                }
            }
            s_qcount = 0;
            s_thr = root;
        }
        __syncthreads();
    }

    // Extract in descending order: pop min K times, fill output back-to-front.
    if (tid == 0) {
        int size = K;
        int* orow = out + (size_t)row * K;
        for (int k = 0; k < K; ++k) {
            unsigned long long top = s_heap[0];
            orow[K - 1 - k] = (int)(~(unsigned)(top & 0xFFFFFFFFull));
            --size;
            unsigned long long x = s_heap[size];
            heap_siftdown(s_heap, size, x);
        }
    }
}

extern "C" void kernel_launch(void* const* d_in, const int* in_sizes, int n_in,
                              void* d_out, int out_size, void* d_ws, size_t ws_size,
                              hipStream_t stream) {
    const float* probs = (const float*)d_in[0];
    const float* rnd   = (const float*)d_in[1];
    int* out = (int*)d_out;

    const int B = out_size / K;            // 1024
    const int V = in_sizes[0] / B;         // 128000

    topk_race_kernel<<<B, BLOCK, 0, stream>>>(probs, rnd, out, V);
}